// Round 1
// baseline (463.984 us; speedup 1.0000x reference)
//
#include <hip/hip_runtime.h>

#define Bsz 4
#define Cin 256
#define Cout 256
#define Hh 64
#define Ww 64
#define HW (Hh * Ww)
#define K9 9
#define CK (Cin * K9)          // 2304
#define NGROUPS 16
#define CPG (Cout / NGROUPS)   // 16
#define EPSV 1e-5f

#define TP 16                  // pixels per block (one row segment)
#define CC 32                  // input-channel chunk staged in LDS

// ---------------------------------------------------------------------------
// Kernel 1: weight transpose  w[o][c][k]  ->  wt[(ck/4)][o][ck%4]  (float4/lane)
// ---------------------------------------------------------------------------
__global__ void wt_kernel(const float* __restrict__ w, float* __restrict__ wt) {
    int i = blockIdx.x * 256 + threadIdx.x;          // over Cout*CK = 589824
    if (i >= Cout * CK) return;
    int o = i / CK;
    int ck = i % CK;
    wt[(((ck >> 2) * Cout) + o) * 4 + (ck & 3)] = w[i];
}

// ---------------------------------------------------------------------------
// Kernel 2: fused deformable sampling + conv (pre-GN result -> out)
// block: 256 threads = 16 pixels x 256 output channels (thread t owns o = t)
// ---------------------------------------------------------------------------
__launch_bounds__(256, 4)
__global__ void dcn_kernel(const float* __restrict__ in,
                           const float* __restrict__ offs,
                           const float* __restrict__ mask,
                           const float* __restrict__ wt,
                           const float* __restrict__ bias,
                           float* __restrict__ out) {
    __shared__ float s_w[4][144];     // corner weights (mask folded in)
    __shared__ int   s_i[4][144];     // clipped corner indices (y*W+x)
    __shared__ float s_col[CC * 144]; // staged samples: [c_local][k*16+p]

    const int t = threadIdx.x;
    const int pix0 = blockIdx.x * TP;
    const int b  = pix0 / HW;
    const int hw0 = pix0 % HW;
    const int h  = hw0 / Ww;
    const int w0 = hw0 % Ww;          // multiple of 16

    // ---- precompute taps: 9 kernel points x 16 pixels ----
    if (t < 144) {
        const int k = t / TP, p = t % TP;
        const int wq = w0 + p;
        const float* offb = offs + (size_t)b * 18 * HW + h * Ww + wq;
        const float dy = offb[(2 * k) * HW];
        const float dx = offb[(2 * k + 1) * HW];
        const float m  = mask[((size_t)b * 9 + k) * HW + h * Ww + wq];
        const float y = (float)h + (float)(k / 3 - 1) + dy;
        const float x = (float)wq + (float)(k % 3 - 1) + dx;
        const float y0 = floorf(y), x0 = floorf(x);
        const float ly = y - y0, lx = x - x0;
        const float hy = 1.f - ly, hx = 1.f - lx;
        const float cy[2] = {y0, y0 + 1.f};
        const float cx[2] = {x0, x0 + 1.f};
        const float wy[2] = {hy, ly};
        const float wx[2] = {hx, lx};
#pragma unroll
        for (int a = 0; a < 2; a++) {
#pragma unroll
            for (int bb = 0; bb < 2; bb++) {
                const float yc = cy[a], xc = cx[bb];
                const bool valid = (yc >= 0.f) && (yc < (float)Hh) &&
                                   (xc >= 0.f) && (xc < (float)Ww);
                const int yi = (int)fminf(fmaxf(yc, 0.f), (float)(Hh - 1));
                const int xi = (int)fminf(fmaxf(xc, 0.f), (float)(Ww - 1));
                s_i[a * 2 + bb][t] = yi * Ww + xi;
                s_w[a * 2 + bb][t] = valid ? (wy[a] * wx[bb] * m) : 0.f;
            }
        }
    }

    float acc[TP];
#pragma unroll
    for (int p = 0; p < TP; p++) acc[p] = 0.f;

    const float* inb = in + (size_t)b * Cin * HW;

    for (int c0 = 0; c0 < Cin; c0 += CC) {
        __syncthreads();  // protects s_col reuse; first iter: publishes taps
        // ---- stage CC x 9 x 16 bilinear samples into LDS ----
        for (int i = t; i < CC * 144; i += 256) {
            const int cl = i / 144, j = i % 144;
            const float* base = inb + (size_t)(c0 + cl) * HW;
            const float v = s_w[0][j] * base[s_i[0][j]] +
                            s_w[1][j] * base[s_i[1][j]] +
                            s_w[2][j] * base[s_i[2][j]] +
                            s_w[3][j] * base[s_i[3][j]];
            s_col[i] = v;
        }
        __syncthreads();
        // ---- GEMM slice: thread t = output channel, 16 pixels ----
        const float4* wp = ((const float4*)wt) + ((c0 * K9) >> 2) * Cout + t;
        const float4* colp = (const float4*)s_col;
#pragma unroll 2
        for (int ckq = 0; ckq < (CC * K9) / 4; ckq++) {
            const float4 wv = wp[ckq * Cout];   // coalesced across lanes
            const float wr[4] = {wv.x, wv.y, wv.z, wv.w};
#pragma unroll
            for (int r = 0; r < 4; r++) {
                const float wf = wr[r];
                const float4* cp = colp + (ckq * 4 + r) * 4; // 16 floats, broadcast
                const float4 a0 = cp[0], a1 = cp[1], a2 = cp[2], a3 = cp[3];
                acc[0]  += wf * a0.x; acc[1]  += wf * a0.y;
                acc[2]  += wf * a0.z; acc[3]  += wf * a0.w;
                acc[4]  += wf * a1.x; acc[5]  += wf * a1.y;
                acc[6]  += wf * a1.z; acc[7]  += wf * a1.w;
                acc[8]  += wf * a2.x; acc[9]  += wf * a2.y;
                acc[10] += wf * a2.z; acc[11] += wf * a2.w;
                acc[12] += wf * a3.x; acc[13] += wf * a3.y;
                acc[14] += wf * a3.z; acc[15] += wf * a3.w;
            }
        }
    }

    // ---- epilogue: bias + store (64 contiguous bytes per thread) ----
    const float bo = bias[t];
    float* op = out + ((size_t)b * Cout + t) * HW + h * Ww + w0;
#pragma unroll
    for (int q = 0; q < TP / 4; q++) {
        float4 v;
        v.x = acc[q * 4 + 0] + bo;
        v.y = acc[q * 4 + 1] + bo;
        v.z = acc[q * 4 + 2] + bo;
        v.w = acc[q * 4 + 3] + bo;
        ((float4*)op)[q] = v;
    }
}

// ---------------------------------------------------------------------------
// Kernel 3: GroupNorm stats — one block per (b,g); slab is contiguous
// ---------------------------------------------------------------------------
__global__ void gn_stats_kernel(const float* __restrict__ x, float* __restrict__ stats) {
    const int bg = blockIdx.x;
    const float4* p4 = (const float4*)(x + (size_t)bg * (CPG * HW));
    float s = 0.f, s2 = 0.f;
    for (int i = threadIdx.x; i < (CPG * HW) / 4; i += 256) {
        const float4 v = p4[i];
        s  += v.x + v.y + v.z + v.w;
        s2 += v.x * v.x + v.y * v.y + v.z * v.z + v.w * v.w;
    }
#pragma unroll
    for (int off = 32; off > 0; off >>= 1) {
        s  += __shfl_down(s, off);
        s2 += __shfl_down(s2, off);
    }
    __shared__ float ls[4], ls2[4];
    const int wid = threadIdx.x >> 6;
    if ((threadIdx.x & 63) == 0) { ls[wid] = s; ls2[wid] = s2; }
    __syncthreads();
    if (threadIdx.x == 0) {
        const float S  = ls[0] + ls[1] + ls[2] + ls[3];
        const float S2 = ls2[0] + ls2[1] + ls2[2] + ls2[3];
        const float n  = (float)(CPG * HW);
        const float mu = S / n;
        const float var = S2 / n - mu * mu;
        stats[bg * 2]     = mu;
        stats[bg * 2 + 1] = rsqrtf(var + EPSV);
    }
}

// ---------------------------------------------------------------------------
// Kernel 4: GroupNorm apply (in place on out)
// ---------------------------------------------------------------------------
__global__ void gn_apply_kernel(float* __restrict__ x, const float* __restrict__ stats,
                                const float* __restrict__ gamma,
                                const float* __restrict__ beta) {
    const int i = blockIdx.x * 256 + threadIdx.x;  // float4 index, exactly 1048576
    const int plane = i >> 10;                     // (b*256 + o), 1024 float4/plane
    const int o = plane & 255;
    const int bg = plane >> 4;                     // b*16 + g
    const float mu = stats[bg * 2], rs = stats[bg * 2 + 1];
    const float ga = gamma[o] * rs;
    const float be = beta[o] - mu * ga;
    float4 v = ((float4*)x)[i];
    v.x = v.x * ga + be;
    v.y = v.y * ga + be;
    v.z = v.z * ga + be;
    v.w = v.w * ga + be;
    ((float4*)x)[i] = v;
}

// ---------------------------------------------------------------------------
extern "C" void kernel_launch(void* const* d_in, const int* in_sizes, int n_in,
                              void* d_out, int out_size, void* d_ws, size_t ws_size,
                              hipStream_t stream) {
    const float* input  = (const float*)d_in[0];
    const float* offset = (const float*)d_in[1];
    const float* maskp  = (const float*)d_in[2];
    const float* weight = (const float*)d_in[3];
    const float* bias   = (const float*)d_in[4];
    const float* gamma  = (const float*)d_in[5];
    const float* beta   = (const float*)d_in[6];
    float* out = (float*)d_out;

    float* wt    = (float*)d_ws;           // Cout*CK floats = 2.36 MB
    float* stats = wt + (size_t)Cout * CK; // 128 floats

    hipLaunchKernelGGL(wt_kernel, dim3((Cout * CK + 255) / 256), dim3(256), 0, stream,
                       weight, wt);
    hipLaunchKernelGGL(dcn_kernel, dim3(Bsz * HW / TP), dim3(256), 0, stream,
                       input, offset, maskp, wt, bias, out);
    hipLaunchKernelGGL(gn_stats_kernel, dim3(Bsz * NGROUPS), dim3(256), 0, stream,
                       out, stats);
    hipLaunchKernelGGL(gn_apply_kernel, dim3((Bsz * Cout * HW / 4) / 256), dim3(256), 0,
                       stream, out, stats, gamma, beta);
}

// Round 2
// 243.441 us; speedup vs baseline: 1.9059x; 1.9059x over previous
//
#include <hip/hip_runtime.h>

typedef __attribute__((ext_vector_type(8))) short short8;   // 8 x bf16 (4 VGPR)
typedef __attribute__((ext_vector_type(4))) float f32x4;
typedef __attribute__((ext_vector_type(4))) int int4v;

#define Bsz 4
#define Cin 256
#define Cout 256
#define Hh 64
#define Ww 64
#define HW 4096
#define NG 16
#define EPSV 1e-5f

#define CSTR 40   // col LDS row stride in ushorts: 32 data + 8 pad = 80 B
                  // keeps ds_read_b128 16B-aligned; bank slots all distinct mod 32

static __device__ __forceinline__ unsigned f2bf(float f) {
    unsigned u = __float_as_uint(f);
    return (u + 0x7fffu + ((u >> 16) & 1u)) >> 16;   // RNE bf16
}

// ---------------------------------------------------------------------------
// Kernel 1: weight reorder w[o][c][kk] -> bf16 wtb[ks][o][32]   (ck' = kk*256+c)
// fragment-order: for K-step ks, row o holds the 32 ck' values contiguously.
// Also zeroes the GN stats accumulators.
// ---------------------------------------------------------------------------
__global__ void wt_kernel(const float* __restrict__ w, ushort* __restrict__ wtb,
                          float* __restrict__ stats) {
    const int i = blockIdx.x * 256 + threadIdx.x;      // over 256*2304 = 589824
    if (blockIdx.x == 0 && threadIdx.x < 128) stats[threadIdx.x] = 0.f;
    if (i >= Cout * Cin * 9) return;
    const int o = i / (Cin * 9);
    const int rem = i % (Cin * 9);
    const int c = rem / 9, kk = rem % 9;
    const int ks = kk * 8 + (c >> 5);                  // 72 K-steps of 32
    wtb[(ks * 256 + o) * 32 + (c & 31)] = (ushort)f2bf(w[i]);
}

// ---------------------------------------------------------------------------
// Kernel 2: fused deformable sampling + bf16 MFMA conv + GN partial stats.
// Block: 512 threads (8 waves) = one image row (b,h): N=64 pixels, M=256 Co.
// Wave wv owns channels [32wv, 32wv+32): 2 m-tiles x 4 n-tiles of 16x16x32.
// ---------------------------------------------------------------------------
__launch_bounds__(512, 2)
__global__ void dcn_kernel(const float* __restrict__ in,
                           const float* __restrict__ offs,
                           const float* __restrict__ mask,
                           const ushort* __restrict__ wtb,
                           const float* __restrict__ bias,
                           float* __restrict__ out,
                           float* __restrict__ stats) {
    __shared__ int    s_ti[9 * 64 * 4];     // [k][n][corner] clipped plane index
    __shared__ float  s_tw[9 * 64 * 4];     // [k][n][corner] bilinear*mask weight
    __shared__ ushort s_col[64 * CSTR];     // [n][32 ck + pad] bf16

    const int t  = threadIdx.x;
    const int bx = blockIdx.x;              // 256 blocks: b*64 + h
    const int b  = bx >> 6, h = bx & 63;
    const int lane = t & 63;
    const int wv   = t >> 6;                // wave 0..7
    const int n    = lane;                  // sampling: pixel in row
    const int quad = lane >> 4;
    const int l15  = lane & 15;

    // ---- tap precompute: 9 kernel points x 64 pixels ----
    for (int j = t; j < 576; j += 512) {
        const int k = j >> 6, p = j & 63;
        const float* ob = offs + (size_t)b * 18 * HW + h * Ww + p;
        const float dy = ob[(2 * k) * HW];
        const float dx = ob[(2 * k + 1) * HW];
        const float m  = mask[((size_t)b * 9 + k) * HW + h * Ww + p];
        const float y = (float)h + (float)(k / 3 - 1) + dy;
        const float x = (float)p + (float)(k % 3 - 1) + dx;
        const float y0 = floorf(y), x0 = floorf(x);
        const float ly = y - y0, lx = x - x0;
        const float hy = 1.f - ly, hx = 1.f - lx;
        const float cy[2] = {y0, y0 + 1.f};
        const float cx[2] = {x0, x0 + 1.f};
        const float wy[2] = {hy, ly};
        const float wx[2] = {hx, lx};
#pragma unroll
        for (int a = 0; a < 2; a++)
#pragma unroll
            for (int bb = 0; bb < 2; bb++) {
                const float yc = cy[a], xc = cx[bb];
                const bool valid = (yc >= 0.f) && (yc < (float)Hh) &&
                                   (xc >= 0.f) && (xc < (float)Ww);
                const int yi = (int)fminf(fmaxf(yc, 0.f), (float)(Hh - 1));
                const int xi = (int)fminf(fmaxf(xc, 0.f), (float)(Ww - 1));
                s_ti[j * 4 + a * 2 + bb] = yi * Ww + xi;
                s_tw[j * 4 + a * 2 + bb] = valid ? (wy[a] * wx[bb] * m) : 0.f;
            }
    }
    __syncthreads();

    f32x4 acc[2][4];
#pragma unroll
    for (int i = 0; i < 2; i++)
#pragma unroll
        for (int nt = 0; nt < 4; nt++) acc[i][nt] = (f32x4){0.f, 0.f, 0.f, 0.f};

    const float* inb = in + (size_t)b * Cin * HW;

    for (int k = 0; k < 9; k++) {
        const int tb = (k * 64 + n) * 4;
        const int4v ti = *(const int4v*)&s_ti[tb];     // broadcast across waves
        const f32x4 tw = *(const f32x4*)&s_tw[tb];
#pragma unroll 1
        for (int cc = 0; cc < 8; cc++) {
            const int ks = k * 8 + cc;
            // A-fragments straight from global (L2-hot, fully coalesced 1KB/wave)
            const ushort* wp = wtb + ((size_t)(ks * 256 + wv * 32 + l15)) * 32 + quad * 8;
            const short8 a0 = *(const short8*)wp;
            const short8 a1 = *(const short8*)(wp + 16 * 32);
            // gather 4 samples: c = cc*32 + wv*4 + j
            const float* cb = inb + (size_t)(cc * 32 + wv * 4) * HW;
            unsigned pk0, pk1;
            {
                const float* p0 = cb;
                const float* p1 = cb + HW;
                const float* p2 = cb + 2 * HW;
                const float* p3 = cb + 3 * HW;
                const float v0 = tw.x * p0[ti.x] + tw.y * p0[ti.y] + tw.z * p0[ti.z] + tw.w * p0[ti.w];
                const float v1 = tw.x * p1[ti.x] + tw.y * p1[ti.y] + tw.z * p1[ti.z] + tw.w * p1[ti.w];
                const float v2 = tw.x * p2[ti.x] + tw.y * p2[ti.y] + tw.z * p2[ti.z] + tw.w * p2[ti.w];
                const float v3 = tw.x * p3[ti.x] + tw.y * p3[ti.y] + tw.z * p3[ti.z] + tw.w * p3[ti.w];
                pk0 = f2bf(v0) | (f2bf(v1) << 16);
                pk1 = f2bf(v2) | (f2bf(v3) << 16);
            }
            __syncthreads();   // WAR: prior iteration's B-reads complete
            *(unsigned long long*)&s_col[n * CSTR + wv * 4] =
                (unsigned long long)pk0 | ((unsigned long long)pk1 << 32);
            __syncthreads();   // RAW: col tile visible
            short8 bfr[4];
#pragma unroll
            for (int nt = 0; nt < 4; nt++)
                bfr[nt] = *(const short8*)&s_col[(nt * 16 + l15) * CSTR + quad * 8];
#pragma unroll
            for (int nt = 0; nt < 4; nt++) {
                acc[0][nt] = __builtin_amdgcn_mfma_f32_16x16x32_bf16(a0, bfr[nt], acc[0][nt], 0, 0, 0);
                acc[1][nt] = __builtin_amdgcn_mfma_f32_16x16x32_bf16(a1, bfr[nt], acc[1][nt], 0, 0, 0);
            }
        }
    }

    // ---- epilogue: bias, store, GN partial stats ----
    float gs[2], gq[2];
#pragma unroll
    for (int i = 0; i < 2; i++) {
        float s = 0.f, q = 0.f;
        const int ob = wv * 32 + i * 16 + quad * 4;
#pragma unroll
        for (int reg = 0; reg < 4; reg++) {
            const int o = ob + reg;
            const float bv = bias[o];
            float* op = out + ((size_t)(b * 256 + o)) * HW + h * Ww + l15;
#pragma unroll
            for (int nt = 0; nt < 4; nt++) {
                const float v = acc[i][nt][reg] + bv;
                op[nt * 16] = v;
                s += v;
                q += v * v;
            }
        }
        gs[i] = s; gq[i] = q;
    }
#pragma unroll
    for (int off = 32; off; off >>= 1) {
        gs[0] += __shfl_xor(gs[0], off);
        gq[0] += __shfl_xor(gq[0], off);
        gs[1] += __shfl_xor(gs[1], off);
        gq[1] += __shfl_xor(gq[1], off);
    }
    if (lane == 0) {
#pragma unroll
        for (int i = 0; i < 2; i++) {
            const int g = wv * 2 + i;                  // channel group of m-tile
            atomicAdd(&stats[((size_t)b * NG + g) * 2],     gs[i]);
            atomicAdd(&stats[((size_t)b * NG + g) * 2 + 1], gq[i]);
        }
    }
}

// ---------------------------------------------------------------------------
// Kernel 3: GN apply (mu/rsqrt from accumulated sums, in place)
// ---------------------------------------------------------------------------
__global__ void gn_apply_kernel(float* __restrict__ x, const float* __restrict__ stats,
                                const float* __restrict__ gamma,
                                const float* __restrict__ beta) {
    const int i = blockIdx.x * 256 + threadIdx.x;      // float4 idx, 1048576 total
    const int plane = i >> 10;                         // b*256 + o
    const int o = plane & 255;
    const int bg = plane >> 4;                         // b*16 + g
    const float s = stats[bg * 2], q = stats[bg * 2 + 1];
    const float inv_n = 1.f / 65536.f;                 // 16 ch * 4096 px
    const float mu = s * inv_n;
    const float var = q * inv_n - mu * mu;
    const float rs = rsqrtf(var + EPSV);
    const float ga = gamma[o] * rs;
    const float be = beta[o] - mu * ga;
    float4 v = ((float4*)x)[i];
    v.x = v.x * ga + be;
    v.y = v.y * ga + be;
    v.z = v.z * ga + be;
    v.w = v.w * ga + be;
    ((float4*)x)[i] = v;
}

// ---------------------------------------------------------------------------
extern "C" void kernel_launch(void* const* d_in, const int* in_sizes, int n_in,
                              void* d_out, int out_size, void* d_ws, size_t ws_size,
                              hipStream_t stream) {
    const float* input  = (const float*)d_in[0];
    const float* offset = (const float*)d_in[1];
    const float* maskp  = (const float*)d_in[2];
    const float* weight = (const float*)d_in[3];
    const float* bias   = (const float*)d_in[4];
    const float* gamma  = (const float*)d_in[5];
    const float* beta   = (const float*)d_in[6];
    float* out = (float*)d_out;

    ushort* wtb  = (ushort*)d_ws;                           // 589824 ushorts = 1.18 MB
    float* stats = (float*)((char*)d_ws + (size_t)Cout * Cin * 9 * sizeof(ushort));

    hipLaunchKernelGGL(wt_kernel, dim3((Cout * Cin * 9 + 255) / 256), dim3(256), 0,
                       stream, weight, wtb, stats);
    hipLaunchKernelGGL(dcn_kernel, dim3(Bsz * Hh), dim3(512), 0, stream,
                       input, offset, maskp, wtb, bias, out, stats);
    hipLaunchKernelGGL(gn_apply_kernel, dim3((Bsz * Cout * HW / 4) / 256), dim3(256), 0,
                       stream, out, stats, gamma, beta);
}

// Round 4
// 216.811 us; speedup vs baseline: 2.1400x; 1.1228x over previous
//
#include <hip/hip_runtime.h>

typedef __attribute__((ext_vector_type(8))) short short8;   // 8 x bf16 (4 VGPR)
typedef __attribute__((ext_vector_type(4))) float f32x4;

#define Bsz 4
#define Cin 256
#define Cout 256
#define Hh 64
#define Ww 64
#define HW 4096
#define NG 16
#define EPSV 1e-5f

#define CSTR 40   // col LDS row stride in ushorts: 32 data + 8 pad = 80 B

static __device__ __forceinline__ unsigned f2bf(float f) {
    unsigned u = __float_as_uint(f);
    return (u + 0x7fffu + ((u >> 16) & 1u)) >> 16;   // RNE bf16
}

static __device__ __forceinline__ float2 ld8(const float* p) {
    float2 v;
    __builtin_memcpy(&v, p, 8);   // 4B-aligned pair load
    return v;
}

// ---------------------------------------------------------------------------
// Kernel 1: weight reorder w[o][c][kk] -> bf16 wtb[ks][o][32],  ks = kk*8 + c/32
// Also zeroes the GN stats accumulators.
// ---------------------------------------------------------------------------
__global__ void wt_kernel(const float* __restrict__ w, ushort* __restrict__ wtb,
                          float* __restrict__ stats) {
    const int i = blockIdx.x * 256 + threadIdx.x;      // over 256*2304 = 589824
    if (blockIdx.x == 0 && threadIdx.x < 128) stats[threadIdx.x] = 0.f;
    if (i >= Cout * Cin * 9) return;
    const int o = i / (Cin * 9);
    const int rem = i % (Cin * 9);
    const int c = rem / 9, kk = rem % 9;
    const int ks = kk * 8 + (c >> 5);                  // 72 K-steps of 32
    wtb[(ks * 256 + o) * 32 + (c & 31)] = (ushort)f2bf(w[i]);
}

// ---------------------------------------------------------------------------
// Kernel 2: fused deformable sampling + bf16 MFMA conv + GN partial stats.
// Block: 512 threads (8 waves) = one image row (b,h): N=64 px, M=256 Co.
// Loop: cc (32-ch chunk) OUTER, kk (tap) INNER -> 9x L1 reuse of plane windows.
// ---------------------------------------------------------------------------
__launch_bounds__(512, 2)
__global__ void dcn_kernel(const float* __restrict__ in,
                           const float* __restrict__ offs,
                           const float* __restrict__ mask,
                           const ushort* __restrict__ wtb,
                           const float* __restrict__ bias,
                           float* __restrict__ out,
                           float* __restrict__ stats) {
    __shared__ int2   s_ta[9 * 64];        // [k][n]: two row base addrs (y*64+xb)
    __shared__ float4 s_tw[9 * 64];        // [k][n]: folded pair weights
    __shared__ ushort s_col[2][64 * CSTR]; // double-buffered col tile (bf16)

    const int t  = threadIdx.x;
    const int bx = blockIdx.x;
    // XCD swizzle: XCD q = bx&7 serves batch q>>1, h-half q&1 (L2 locality)
    const int q  = bx & 7, r = bx >> 3;
    const int b  = q >> 1;
    const int h  = ((q & 1) << 5) | r;
    const int lane = t & 63;
    const int wv   = t >> 6;               // wave 0..7
    const int n    = lane;                 // pixel in row
    const int quad = lane >> 4;
    const int l15  = lane & 15;

    // ---- tap precompute: 9 kernel points x 64 pixels ----
    for (int j = t; j < 576; j += 512) {
        const int k = j >> 6, p = j & 63;
        const float* ob = offs + (size_t)b * 18 * HW + h * Ww + p;
        const float dy = ob[(2 * k) * HW];
        const float dx = ob[(2 * k + 1) * HW];
        const float m  = mask[((size_t)b * 9 + k) * HW + h * Ww + p];
        const float y = (float)h + (float)(k / 3 - 1) + dy;
        const float x = (float)p + (float)(k % 3 - 1) + dx;
        const float y0f = floorf(y), x0f = floorf(x);
        const float ly = y - y0f, lx = x - x0f;
        const float hy = 1.f - ly, hx = 1.f - lx;
        const int y0 = (int)y0f, x0 = (int)x0f;
        const int yc0 = min(max(y0, 0), 63);
        const int yc1 = min(max(y0 + 1, 0), 63);
        const int xb  = min(max(x0, 0), 62);
        // col-remapped pair coefficients (corner validity folded):
        //   v.x = row[xb], v.y = row[xb+1]
        float ax = 0.f, ay = 0.f;
        if (x0 == xb) {                       // x0 in [0,62]: both corners in-row
            ax = hx;                          // corner x0   -> v.x
            ay = lx;                          // corner x0+1 (<=63) -> v.y
        } else if (x0 < xb) {                 // x0 < 0
            ax = (x0 + 1 == 0) ? lx : 0.f;    // only corner x0+1==0 can be valid
        } else {                              // x0 > 62
            ay = (x0 == 63) ? hx : 0.f;       // x0==63: corner 63 -> v.y;
                                              // x0>=64: both corners OOB -> 0
        }
        const float w0 = (y0 >= 0 && y0 < 64) ? m * hy : 0.f;
        const float w1 = (y0 + 1 >= 0 && y0 + 1 < 64) ? m * ly : 0.f;
        s_ta[j] = make_int2(yc0 * 64 + xb, yc1 * 64 + xb);
        s_tw[j] = make_float4(w0 * ax, w0 * ay, w1 * ax, w1 * ay);
    }
    __syncthreads();

    f32x4 acc[2][4];
#pragma unroll
    for (int i = 0; i < 2; i++)
#pragma unroll
        for (int nt = 0; nt < 4; nt++) acc[i][nt] = (f32x4){0.f, 0.f, 0.f, 0.f};

    const float* inb = in + (size_t)b * Cin * HW;

    // gather 4 samples for step (cc,kk): c = cc*32 + wv*4 + j, pixel n
#define GATHER(cc, kk, pk0, pk1)                                           \
    {                                                                      \
        const int2  ad = s_ta[(kk) * 64 + n];                              \
        const float4 tw = s_tw[(kk) * 64 + n];                             \
        const float* cb = inb + (size_t)((cc) * 32 + wv * 4) * HW;         \
        float vv[4];                                                       \
        _Pragma("unroll")                                                  \
        for (int j = 0; j < 4; j++) {                                      \
            const float* pl = cb + j * HW;                                 \
            const float2 g0 = ld8(pl + ad.x);                              \
            const float2 g1 = ld8(pl + ad.y);                              \
            vv[j] = tw.x * g0.x + tw.y * g0.y + tw.z * g1.x + tw.w * g1.y; \
        }                                                                  \
        pk0 = f2bf(vv[0]) | (f2bf(vv[1]) << 16);                           \
        pk1 = f2bf(vv[2]) | (f2bf(vv[3]) << 16);                           \
    }

    unsigned pk0, pk1;
    GATHER(0, 0, pk0, pk1);                  // prologue: step 0

    int p = 0;
#pragma unroll 1
    for (int s = 0; s < 72; s++) {
        const int cc = s / 9;
        const int kk = s - cc * 9;
        const int ks = kk * 8 + cc;          // K-step index in weight layout
        // publish current samples
        *(unsigned long long*)&s_col[p][n * CSTR + wv * 4] =
            (unsigned long long)pk0 | ((unsigned long long)pk1 << 32);
        __syncthreads();
        // pipelined gather for next step (overlaps MFMA below)
        if (s < 71) {
            const int s1 = s + 1;
            const int cc1 = s1 / 9;
            GATHER(cc1, s1 - cc1 * 9, pk0, pk1);
        }
        // A-fragments straight from global (L2-hot, coalesced 1KB/wave)
        const ushort* wp = wtb + ((size_t)(ks * 256 + wv * 32 + l15)) * 32 + quad * 8;
        const short8 a0 = *(const short8*)wp;
        const short8 a1 = *(const short8*)(wp + 16 * 32);
        short8 bfr[4];
#pragma unroll
        for (int nt = 0; nt < 4; nt++)
            bfr[nt] = *(const short8*)&s_col[p][(nt * 16 + l15) * CSTR + quad * 8];
#pragma unroll
        for (int nt = 0; nt < 4; nt++) {
            acc[0][nt] = __builtin_amdgcn_mfma_f32_16x16x32_bf16(a0, bfr[nt], acc[0][nt], 0, 0, 0);
            acc[1][nt] = __builtin_amdgcn_mfma_f32_16x16x32_bf16(a1, bfr[nt], acc[1][nt], 0, 0, 0);
        }
        p ^= 1;
    }
#undef GATHER

    // ---- epilogue: bias, store, GN partial stats ----
    float gs[2], gq[2];
#pragma unroll
    for (int i = 0; i < 2; i++) {
        float s = 0.f, qq = 0.f;
        const int ob = wv * 32 + i * 16 + quad * 4;
#pragma unroll
        for (int reg = 0; reg < 4; reg++) {
            const int o = ob + reg;
            const float bv = bias[o];
            float* op = out + ((size_t)(b * 256 + o)) * HW + h * Ww + l15;
#pragma unroll
            for (int nt = 0; nt < 4; nt++) {
                const float v = acc[i][nt][reg] + bv;
                op[nt * 16] = v;
                s += v;
                qq += v * v;
            }
        }
        gs[i] = s; gq[i] = qq;
    }
#pragma unroll
    for (int off = 32; off; off >>= 1) {
        gs[0] += __shfl_xor(gs[0], off);
        gq[0] += __shfl_xor(gq[0], off);
        gs[1] += __shfl_xor(gs[1], off);
        gq[1] += __shfl_xor(gq[1], off);
    }
    if (lane == 0) {
#pragma unroll
        for (int i = 0; i < 2; i++) {
            const int g = wv * 2 + i;
            atomicAdd(&stats[((size_t)b * NG + g) * 2],     gs[i]);
            atomicAdd(&stats[((size_t)b * NG + g) * 2 + 1], gq[i]);
        }
    }
}

// ---------------------------------------------------------------------------
// Kernel 3: GN apply (mu/rsqrt from accumulated sums, in place)
// ---------------------------------------------------------------------------
__global__ void gn_apply_kernel(float* __restrict__ x, const float* __restrict__ stats,
                                const float* __restrict__ gamma,
                                const float* __restrict__ beta) {
    const int i = blockIdx.x * 256 + threadIdx.x;      // float4 idx, 1048576 total
    const int plane = i >> 10;                         // b*256 + o
    const int o = plane & 255;
    const int bg = plane >> 4;                         // b*16 + g
    const float s = stats[bg * 2], q = stats[bg * 2 + 1];
    const float inv_n = 1.f / 65536.f;
    const float mu = s * inv_n;
    const float var = q * inv_n - mu * mu;
    const float rs = rsqrtf(var + EPSV);
    const float ga = gamma[o] * rs;
    const float be = beta[o] - mu * ga;
    float4 v = ((float4*)x)[i];
    v.x = v.x * ga + be;
    v.y = v.y * ga + be;
    v.z = v.z * ga + be;
    v.w = v.w * ga + be;
    ((float4*)x)[i] = v;
}

// ---------------------------------------------------------------------------
extern "C" void kernel_launch(void* const* d_in, const int* in_sizes, int n_in,
                              void* d_out, int out_size, void* d_ws, size_t ws_size,
                              hipStream_t stream) {
    const float* input  = (const float*)d_in[0];
    const float* offset = (const float*)d_in[1];
    const float* maskp  = (const float*)d_in[2];
    const float* weight = (const float*)d_in[3];
    const float* bias   = (const float*)d_in[4];
    const float* gamma  = (const float*)d_in[5];
    const float* beta   = (const float*)d_in[6];
    float* out = (float*)d_out;

    ushort* wtb  = (ushort*)d_ws;                           // 1.18 MB
    float* stats = (float*)((char*)d_ws + (size_t)Cout * Cin * 9 * sizeof(ushort));

    hipLaunchKernelGGL(wt_kernel, dim3((Cout * Cin * 9 + 255) / 256), dim3(256), 0,
                       stream, weight, wtb, stats);
    hipLaunchKernelGGL(dcn_kernel, dim3(Bsz * Hh), dim3(512), 0, stream,
                       input, offset, maskp, wtb, bias, out, stats);
    hipLaunchKernelGGL(gn_apply_kernel, dim3((Bsz * Cout * HW / 4) / 256), dim3(256), 0,
                       stream, out, stats, gamma, beta);
}